// Round 1
// baseline (690.698 us; speedup 1.0000x reference)
//
#include <hip/hip_runtime.h>

typedef __attribute__((ext_vector_type(8))) short bf16x8;   // 8 bf16 (4 VGPRs), per guide
typedef __attribute__((ext_vector_type(4))) float f32x4;

#define D_MODEL 1024
#define T_LEN 2048
#define BATCH 2
#define N_HEADS 16
#define D_HEAD 64
#define WINDOW 256
#define N_STATE 128
#define D_FF 4096
#define N_CAT 4224   // 4*D_MODEL + N_STATE
#define M_ROWS 4096  // B*T

static __device__ __forceinline__ float bf2f(unsigned short u) {
  union { unsigned int i; float f; } v; v.i = ((unsigned int)u) << 16; return v.f;
}
static __device__ __forceinline__ unsigned short f2bf(float f) {
  unsigned int x = __float_as_uint(f);
  return (unsigned short)((x + 0x7FFFu + ((x >> 16) & 1u)) >> 16);
}

// ---------------------------------------------------------------------------
// Transpose + f32->bf16 convert: dst[(n_off+n)*ldd + k] = bf16(src[k*N + n])
// ---------------------------------------------------------------------------
__global__ __launch_bounds__(256) void transpose_cvt(
    const float* __restrict__ src, unsigned short* __restrict__ dst,
    int K, int N, int n_off, int ldd)
{
  __shared__ float tile[32][33];
  const int kt = blockIdx.x * 32, nt = blockIdx.y * 32;
  const int c = threadIdx.x & 31, r0 = threadIdx.x >> 5;
#pragma unroll
  for (int i = 0; i < 4; i++) {
    const int r = r0 + i * 8;
    tile[r][c] = src[(size_t)(kt + r) * N + nt + c];
  }
  __syncthreads();
#pragma unroll
  for (int i = 0; i < 4; i++) {
    const int r = r0 + i * 8;
    dst[(size_t)(n_off + nt + r) * ldd + kt + c] = f2bf(tile[c][r]);
  }
}

__global__ __launch_bounds__(256) void build_bcat(
    const float* __restrict__ bq, const float* __restrict__ bk,
    const float* __restrict__ bv, const float* __restrict__ bg,
    float* __restrict__ bcat)
{
  const int i = blockIdx.x * 256 + threadIdx.x;
  if (i < N_CAT) {
    float v = 0.0f;
    if (i < 1024)      v = bq[i];
    else if (i < 2048) v = bk[i - 1024];
    else if (i < 3072) v = bv[i - 2048];
    else if (i < 4096) v = bg[i - 3072];
    bcat[i] = v;
  }
}

// ---------------------------------------------------------------------------
// LayerNorm: one block per row (1024 cols), bf16 output
// ---------------------------------------------------------------------------
__global__ __launch_bounds__(256) void ln_kernel(
    const float* __restrict__ x, const float* __restrict__ g,
    const float* __restrict__ b, unsigned short* __restrict__ out)
{
  const int row = blockIdx.x, tid = threadIdx.x;
  const float4 xv = ((const float4*)(x + (size_t)row * 1024))[tid];
  float s  = xv.x + xv.y + xv.z + xv.w;
  float s2 = xv.x * xv.x + xv.y * xv.y + xv.z * xv.z + xv.w * xv.w;
#pragma unroll
  for (int off = 32; off >= 1; off >>= 1) {
    s  += __shfl_down(s, off);
    s2 += __shfl_down(s2, off);
  }
  __shared__ float red[8];
  const int wave = tid >> 6;
  if ((tid & 63) == 0) { red[wave] = s; red[4 + wave] = s2; }
  __syncthreads();
  s  = red[0] + red[1] + red[2] + red[3];
  s2 = red[4] + red[5] + red[6] + red[7];
  const float mu = s * (1.0f / 1024.0f);
  const float rs = rsqrtf(s2 * (1.0f / 1024.0f) - mu * mu + 1e-5f);
  const float4 gv = ((const float4*)g)[tid];
  const float4 bv = ((const float4*)b)[tid];
  ushort4 o;
  o.x = f2bf((xv.x - mu) * rs * gv.x + bv.x);
  o.y = f2bf((xv.y - mu) * rs * gv.y + bv.y);
  o.z = f2bf((xv.z - mu) * rs * gv.z + bv.z);
  o.w = f2bf((xv.w - mu) * rs * gv.w + bv.w);
  ((ushort4*)(out + (size_t)row * 1024))[tid] = o;
}

// ---------------------------------------------------------------------------
// GEMM C[M,N] = A[M,K] @ BT[N,K]^T (+bias, +activation, +residual)
// bf16 inputs, 128x128 tile, BK=32, 4 waves of 64x64, mfma 16x16x32
// ACT: 0=none, 2=gelu(exact). OUT_BF16: bf16 vs f32 out. RESID: += resid[idx]
// ---------------------------------------------------------------------------
template<int ACT, bool OUT_BF16, bool RESID>
__global__ __launch_bounds__(256) void gemm_bt(
    const unsigned short* __restrict__ A, const unsigned short* __restrict__ BT,
    const float* __restrict__ bias, const float* __restrict__ resid,
    void* __restrict__ Cout, int M, int N, int K)
{
  __shared__ unsigned short As[128][40];
  __shared__ unsigned short Bs[128][40];
  const int m0 = blockIdx.x * 128, n0 = blockIdx.y * 128;
  const int tid = threadIdx.x, lane = tid & 63, wave = tid >> 6;
  const int wm = (wave >> 1) * 64, wn = (wave & 1) * 64;
  f32x4 acc[4][4];
#pragma unroll
  for (int i = 0; i < 4; i++)
#pragma unroll
    for (int j = 0; j < 4; j++) acc[i][j] = (f32x4){0.f, 0.f, 0.f, 0.f};

  const int r0 = tid >> 2;              // 0..63
  const int c8 = (tid & 3) << 3;        // 0,8,16,24
  const unsigned short* Abase = A  + (size_t)(m0 + r0) * K + c8;
  const unsigned short* Bbase = BT + (size_t)(n0 + r0) * K + c8;
  const size_t rowstride = (size_t)64 * K;

  for (int k0 = 0; k0 < K; k0 += 32) {
    __syncthreads();
    const uint4 a0 = *(const uint4*)(Abase + k0);
    const uint4 a1 = *(const uint4*)(Abase + rowstride + k0);
    const uint4 b0 = *(const uint4*)(Bbase + k0);
    const uint4 b1 = *(const uint4*)(Bbase + rowstride + k0);
    *(uint4*)&As[r0][c8]      = a0;
    *(uint4*)&As[r0 + 64][c8] = a1;
    *(uint4*)&Bs[r0][c8]      = b0;
    *(uint4*)&Bs[r0 + 64][c8] = b1;
    __syncthreads();
    bf16x8 af[4], bfr[4];
#pragma unroll
    for (int mi = 0; mi < 4; mi++)
      af[mi] = *(const bf16x8*)&As[wm + mi * 16 + (lane & 15)][(lane >> 4) * 8];
#pragma unroll
    for (int ni = 0; ni < 4; ni++)
      bfr[ni] = *(const bf16x8*)&Bs[wn + ni * 16 + (lane & 15)][(lane >> 4) * 8];
#pragma unroll
    for (int mi = 0; mi < 4; mi++)
#pragma unroll
      for (int ni = 0; ni < 4; ni++)
        acc[mi][ni] = __builtin_amdgcn_mfma_f32_16x16x32_bf16(af[mi], bfr[ni], acc[mi][ni], 0, 0, 0);
  }

  const int cg = lane >> 4, cc = lane & 15;
#pragma unroll
  for (int ni = 0; ni < 4; ni++) {
    const int col = n0 + wn + ni * 16 + cc;
    const float bv = bias ? bias[col] : 0.0f;
#pragma unroll
    for (int mi = 0; mi < 4; mi++) {
      const int rbase = m0 + wm + mi * 16 + cg * 4;
#pragma unroll
      for (int r = 0; r < 4; r++) {
        float v = acc[mi][ni][r] + bv;
        if (ACT == 2) v = 0.5f * v * (1.0f + erff(v * 0.70710678118654752f));
        const size_t idx = (size_t)(rbase + r) * N + col;
        if (RESID) v += resid[idx];
        if (OUT_BF16) ((unsigned short*)Cout)[idx] = f2bf(v);
        else          ((float*)Cout)[idx] = v;
      }
    }
  }
}

// ---------------------------------------------------------------------------
// Windowed causal attention. One block per (16-query tile, head, batch).
// QK^T via MFMA directly from global (bf16), softmax in LDS, vector PV.
// ---------------------------------------------------------------------------
__global__ __launch_bounds__(256) void attn_kernel(
    const unsigned short* __restrict__ qkvgu, unsigned short* __restrict__ ao)
{
  const int q0 = blockIdx.x * 16;
  const int h  = blockIdx.y;
  const int b  = blockIdx.z;
  const int tid = threadIdx.x, lane = tid & 63, wave = tid >> 6;
  __shared__ float S[16][276];
  const size_t rowbase = (size_t)b * T_LEN;
  const int l15 = lane & 15, lg = lane >> 4;

  bf16x8 aq0, aq1;
  {
    const unsigned short* qp = qkvgu + (rowbase + q0 + l15) * N_CAT + h * 64 + lg * 8;
    aq0 = *(const bf16x8*)qp;
    aq1 = *(const bf16x8*)(qp + 32);
  }
  for (int kt = wave; kt < 17; kt += 4) {
    const int kbase = q0 - 256 + kt * 16;
    const int krow = kbase + l15;
    const int krc = krow < 0 ? 0 : krow;
    const unsigned short* kp = qkvgu + (rowbase + krc) * N_CAT + 1024 + h * 64 + lg * 8;
    const bf16x8 bk0 = *(const bf16x8*)kp;
    const bf16x8 bk1 = *(const bf16x8*)(kp + 32);
    f32x4 sacc = (f32x4){0.f, 0.f, 0.f, 0.f};
    sacc = __builtin_amdgcn_mfma_f32_16x16x32_bf16(aq0, bk0, sacc, 0, 0, 0);
    sacc = __builtin_amdgcn_mfma_f32_16x16x32_bf16(aq1, bk1, sacc, 0, 0, 0);
#pragma unroll
    for (int r = 0; r < 4; r++) {
      const int qi = q0 + lg * 4 + r;
      const int kj = kbase + l15;
      const bool ok = (kj >= 0) && (kj <= qi) && (qi - kj < WINDOW);
      S[lg * 4 + r][kt * 16 + l15] = ok ? sacc[r] * 0.125f : -1e30f;
    }
  }
  __syncthreads();

  const int q = tid >> 4, sub = tid & 15;
  float mx = -1e30f;
  for (int c = sub; c < 272; c += 16) mx = fmaxf(mx, S[q][c]);
#pragma unroll
  for (int off = 8; off >= 1; off >>= 1) mx = fmaxf(mx, __shfl_xor(mx, off));
  float sum = 0.f;
  for (int c = sub; c < 272; c += 16) {
    const float pe = __expf(S[q][c] - mx);
    S[q][c] = pe;
    sum += pe;
  }
#pragma unroll
  for (int off = 8; off >= 1; off >>= 1) sum += __shfl_xor(sum, off);
  const float inv = 1.0f / sum;
  for (int c = sub; c < 272; c += 16) S[q][c] *= inv;
  __syncthreads();

  const int d0 = sub * 4;
  float o0 = 0.f, o1 = 0.f, o2 = 0.f, o3 = 0.f;
  const int kstart = (q0 >= 256) ? 0 : (256 - q0);
  for (int k = kstart; k < 272; k++) {
    const float p = S[q][k];
    const int vrow = q0 - 256 + k;
    const ushort4 vv = *(const ushort4*)(qkvgu + (rowbase + vrow) * N_CAT + 2048 + h * 64 + d0);
    o0 = fmaf(p, bf2f(vv.x), o0);
    o1 = fmaf(p, bf2f(vv.y), o1);
    o2 = fmaf(p, bf2f(vv.z), o2);
    o3 = fmaf(p, bf2f(vv.w), o3);
  }
  ushort4 ov;
  ov.x = f2bf(o0); ov.y = f2bf(o1); ov.z = f2bf(o2); ov.w = f2bf(o3);
  *(ushort4*)(ao + (rowbase + q0 + q) * D_MODEL + h * 64 + d0) = ov;
}

// ---------------------------------------------------------------------------
// Diagonal SSM scan: s_t = A*s_{t-1} + u_t.  One lane per (b, n).
// ---------------------------------------------------------------------------
__global__ __launch_bounds__(256) void scan_kernel(
    const unsigned short* __restrict__ qkvgu, const float* __restrict__ Avec,
    const float* __restrict__ s0, unsigned short* __restrict__ states,
    float* __restrict__ out_state)
{
  const int tid = threadIdx.x;
  const int b = tid >> 7, n = tid & 127;
  const float a = Avec[n];
  float s = s0[b * 128 + n];
  const unsigned short* up = qkvgu + (size_t)b * T_LEN * N_CAT + 4096 + n;
  unsigned short* sp = states + (size_t)b * T_LEN * N_STATE + n;
#pragma unroll 8
  for (int t = 0; t < T_LEN; t++) {
    const float u = bf2f(up[(size_t)t * N_CAT]);
    s = fmaf(a, s, u);
    sp[(size_t)t * N_STATE] = f2bf(s);
  }
  out_state[b * 128 + n] = s;
}

// ---------------------------------------------------------------------------
// Gated fusion: out = x + g*attn + (1-g)*ssm,  g = sigmoid(xg)
// ---------------------------------------------------------------------------
__global__ __launch_bounds__(256) void fusion_kernel(
    const float* __restrict__ x, const unsigned short* __restrict__ qkvgu,
    const unsigned short* __restrict__ attn, const unsigned short* __restrict__ ssm,
    float* __restrict__ out)
{
  const int i = blockIdx.x * 256 + threadIdx.x;   // 1,048,576 float4 groups
  const size_t e4 = (size_t)i * 4;
  const int row = i >> 8;
  const int col = (i & 255) * 4;
  const float4 xv = *(const float4*)(x + e4);
  const ushort4 au = *(const ushort4*)(attn + e4);
  const ushort4 su = *(const ushort4*)(ssm + e4);
  const ushort4 gu = *(const ushort4*)(qkvgu + (size_t)row * N_CAT + 3072 + col);
  float4 o;
  {
    const float g0 = 1.0f / (1.0f + __expf(-bf2f(gu.x)));
    const float g1 = 1.0f / (1.0f + __expf(-bf2f(gu.y)));
    const float g2 = 1.0f / (1.0f + __expf(-bf2f(gu.z)));
    const float g3 = 1.0f / (1.0f + __expf(-bf2f(gu.w)));
    o.x = xv.x + g0 * bf2f(au.x) + (1.0f - g0) * bf2f(su.x);
    o.y = xv.y + g1 * bf2f(au.y) + (1.0f - g1) * bf2f(su.y);
    o.z = xv.z + g2 * bf2f(au.z) + (1.0f - g2) * bf2f(su.z);
    o.w = xv.w + g3 * bf2f(au.w) + (1.0f - g3) * bf2f(su.w);
  }
  *(float4*)(out + e4) = o;
}

// ---------------------------------------------------------------------------
extern "C" void kernel_launch(void* const* d_in, const int* in_sizes, int n_in,
                              void* d_out, int out_size, void* d_ws, size_t ws_size,
                              hipStream_t stream)
{
  const float* x     = (const float*)d_in[0];
  const float* ssm0  = (const float*)d_in[1];
  const float* ln1_g = (const float*)d_in[2];
  const float* ln1_b = (const float*)d_in[3];
  const float* wq    = (const float*)d_in[4];
  const float* bq    = (const float*)d_in[5];
  const float* wk    = (const float*)d_in[6];
  const float* bk    = (const float*)d_in[7];
  const float* wv    = (const float*)d_in[8];
  const float* bv    = (const float*)d_in[9];
  const float* wo    = (const float*)d_in[10];
  const float* bo    = (const float*)d_in[11];
  const float* wg    = (const float*)d_in[12];
  const float* bg    = (const float*)d_in[13];
  const float* Av    = (const float*)d_in[14];
  const float* Bw    = (const float*)d_in[15];
  const float* Cw    = (const float*)d_in[16];
  const float* ln2_g = (const float*)d_in[17];
  const float* ln2_b = (const float*)d_in[18];
  const float* w1    = (const float*)d_in[19];
  const float* b1    = (const float*)d_in[20];
  const float* w2    = (const float*)d_in[21];
  const float* b2    = (const float*)d_in[22];

  char* p = (char*)d_ws;
  auto take = [&](size_t bytes) { char* q = p; p += (bytes + 255) & ~(size_t)255; return q; };
  unsigned short* WcatT  = (unsigned short*)take((size_t)N_CAT * 1024 * 2);
  unsigned short* woT    = (unsigned short*)take((size_t)1024 * 1024 * 2);
  unsigned short* CwT    = (unsigned short*)take((size_t)1024 * 128 * 2);
  unsigned short* w1T    = (unsigned short*)take((size_t)4096 * 1024 * 2);
  unsigned short* w2T    = (unsigned short*)take((size_t)1024 * 4096 * 2);
  float*          bcat   = (float*)take((size_t)N_CAT * 4);
  unsigned short* xn     = (unsigned short*)take((size_t)M_ROWS * 1024 * 2);
  unsigned short* qkvgu  = (unsigned short*)take((size_t)M_ROWS * N_CAT * 2);
  unsigned short* ao     = (unsigned short*)take((size_t)M_ROWS * 1024 * 2);
  unsigned short* states = (unsigned short*)take((size_t)M_ROWS * N_STATE * 2);
  unsigned short* attn_o = (unsigned short*)take((size_t)M_ROWS * 1024 * 2);
  unsigned short* ssm_o  = (unsigned short*)take((size_t)M_ROWS * 1024 * 2);
  unsigned short* hbuf   = qkvgu;   // alias: qkvgu dead after fusion, hbuf used after

  float* outx = (float*)d_out;
  float* out_state = outx + (size_t)M_ROWS * 1024;

  // --- weight prep (bf16, transposed) ---
  transpose_cvt<<<dim3(32, 32), 256, 0, stream>>>(wq, WcatT, 1024, 1024, 0, 1024);
  transpose_cvt<<<dim3(32, 32), 256, 0, stream>>>(wk, WcatT, 1024, 1024, 1024, 1024);
  transpose_cvt<<<dim3(32, 32), 256, 0, stream>>>(wv, WcatT, 1024, 1024, 2048, 1024);
  transpose_cvt<<<dim3(32, 32), 256, 0, stream>>>(wg, WcatT, 1024, 1024, 3072, 1024);
  transpose_cvt<<<dim3(32, 4), 256, 0, stream>>>(Bw, WcatT, 1024, 128, 4096, 1024);
  transpose_cvt<<<dim3(32, 32), 256, 0, stream>>>(wo, woT, 1024, 1024, 0, 1024);
  transpose_cvt<<<dim3(4, 32), 256, 0, stream>>>(Cw, CwT, 128, 1024, 0, 128);
  transpose_cvt<<<dim3(32, 128), 256, 0, stream>>>(w1, w1T, 1024, 4096, 0, 1024);
  transpose_cvt<<<dim3(128, 32), 256, 0, stream>>>(w2, w2T, 4096, 1024, 0, 4096);
  build_bcat<<<17, 256, 0, stream>>>(bq, bk, bv, bg, bcat);

  // --- forward ---
  ln_kernel<<<M_ROWS, 256, 0, stream>>>(x, ln1_g, ln1_b, xn);
  gemm_bt<0, true, false><<<dim3(32, 33), 256, 0, stream>>>(
      xn, WcatT, bcat, nullptr, qkvgu, M_ROWS, N_CAT, 1024);
  attn_kernel<<<dim3(128, 16, 2), 256, 0, stream>>>(qkvgu, ao);
  scan_kernel<<<1, 256, 0, stream>>>(qkvgu, Av, ssm0, states, out_state);
  gemm_bt<0, true, false><<<dim3(32, 8), 256, 0, stream>>>(
      ao, woT, bo, nullptr, attn_o, M_ROWS, 1024, 1024);
  gemm_bt<0, true, false><<<dim3(32, 8), 256, 0, stream>>>(
      states, CwT, nullptr, nullptr, ssm_o, M_ROWS, 1024, 128);
  fusion_kernel<<<4096, 256, 0, stream>>>(x, qkvgu, attn_o, ssm_o, outx);
  ln_kernel<<<M_ROWS, 256, 0, stream>>>(outx, ln2_g, ln2_b, xn);
  gemm_bt<2, true, false><<<dim3(32, 32), 256, 0, stream>>>(
      xn, w1T, b1, nullptr, hbuf, M_ROWS, D_FF, 1024);
  gemm_bt<0, false, true><<<dim3(32, 8), 256, 0, stream>>>(
      hbuf, w2T, b2, outx, outx, M_ROWS, 1024, D_FF);
}

// Round 2
// 422.471 us; speedup vs baseline: 1.6349x; 1.6349x over previous
//
#include <hip/hip_runtime.h>

typedef __attribute__((ext_vector_type(8))) short bf16x8;
typedef __attribute__((ext_vector_type(4))) float f32x4;

#define D_MODEL 1024
#define T_LEN 2048
#define BATCH 2
#define N_HEADS 16
#define D_HEAD 64
#define WINDOW 256
#define N_STATE 128
#define D_FF 4096
#define N_CAT 4224   // 4*D_MODEL + N_STATE
#define M_ROWS 4096  // B*T

static __device__ __forceinline__ float bf2f(unsigned short u) {
  union { unsigned int i; float f; } v; v.i = ((unsigned int)u) << 16; return v.f;
}
static __device__ __forceinline__ unsigned short f2bf(float f) {
  unsigned int x = __float_as_uint(f);
  return (unsigned short)((x + 0x7FFFu + ((x >> 16) & 1u)) >> 16);
}

// async global->LDS, 16B per lane; LDS dest must be wave-uniform base + lane*16
static __device__ __forceinline__ void gl_lds16(const unsigned short* g, unsigned short* l) {
  __builtin_amdgcn_global_load_lds(
      (const __attribute__((address_space(1))) unsigned int*)g,
      (__attribute__((address_space(3))) unsigned int*)l, 16, 0, 0);
}

// ---------------------------------------------------------------------------
// Transpose + f32->bf16 convert: dst[(n_off+n)*ldd + k] = bf16(src[k*N + n])
// ---------------------------------------------------------------------------
__global__ __launch_bounds__(256) void transpose_cvt(
    const float* __restrict__ src, unsigned short* __restrict__ dst,
    int K, int N, int n_off, int ldd)
{
  __shared__ float tile[32][33];
  const int kt = blockIdx.x * 32, nt = blockIdx.y * 32;
  const int c = threadIdx.x & 31, r0 = threadIdx.x >> 5;
#pragma unroll
  for (int i = 0; i < 4; i++) {
    const int r = r0 + i * 8;
    tile[r][c] = src[(size_t)(kt + r) * N + nt + c];
  }
  __syncthreads();
#pragma unroll
  for (int i = 0; i < 4; i++) {
    const int r = r0 + i * 8;
    dst[(size_t)(n_off + nt + r) * ldd + kt + c] = f2bf(tile[c][r]);
  }
}

__global__ __launch_bounds__(256) void build_bcat(
    const float* __restrict__ bq, const float* __restrict__ bk,
    const float* __restrict__ bv, const float* __restrict__ bg,
    float* __restrict__ bcat)
{
  const int i = blockIdx.x * 256 + threadIdx.x;
  if (i < N_CAT) {
    float v = 0.0f;
    if (i < 1024)      v = bq[i];
    else if (i < 2048) v = bk[i - 1024];
    else if (i < 3072) v = bv[i - 2048];
    else if (i < 4096) v = bg[i - 3072];
    bcat[i] = v;
  }
}

// ---------------------------------------------------------------------------
// LayerNorm: one block per row (1024 cols), bf16 output
// ---------------------------------------------------------------------------
__global__ __launch_bounds__(256) void ln_kernel(
    const float* __restrict__ x, const float* __restrict__ g,
    const float* __restrict__ b, unsigned short* __restrict__ out)
{
  const int row = blockIdx.x, tid = threadIdx.x;
  const float4 xv = ((const float4*)(x + (size_t)row * 1024))[tid];
  float s  = xv.x + xv.y + xv.z + xv.w;
  float s2 = xv.x * xv.x + xv.y * xv.y + xv.z * xv.z + xv.w * xv.w;
#pragma unroll
  for (int off = 32; off >= 1; off >>= 1) {
    s  += __shfl_down(s, off);
    s2 += __shfl_down(s2, off);
  }
  __shared__ float red[8];
  const int wave = tid >> 6;
  if ((tid & 63) == 0) { red[wave] = s; red[4 + wave] = s2; }
  __syncthreads();
  s  = red[0] + red[1] + red[2] + red[3];
  s2 = red[4] + red[5] + red[6] + red[7];
  const float mu = s * (1.0f / 1024.0f);
  const float rs = rsqrtf(s2 * (1.0f / 1024.0f) - mu * mu + 1e-5f);
  const float4 gv = ((const float4*)g)[tid];
  const float4 bv = ((const float4*)b)[tid];
  ushort4 o;
  o.x = f2bf((xv.x - mu) * rs * gv.x + bv.x);
  o.y = f2bf((xv.y - mu) * rs * gv.y + bv.y);
  o.z = f2bf((xv.z - mu) * rs * gv.z + bv.z);
  o.w = f2bf((xv.w - mu) * rs * gv.w + bv.w);
  ((ushort4*)(out + (size_t)row * 1024))[tid] = o;
}

// ---------------------------------------------------------------------------
// GEMM C[M,N] = A[M,K] @ BT[N,K]^T (+bias, +activation, +residual)
// bf16, 128xBN tile, BK=32, global_load_lds staging (linear LDS, m97 pattern)
// BN=128: 4 waves of 64x64.  BN=64: 4 waves of 64x32 (2 blocks/CU for N=1024)
// ---------------------------------------------------------------------------
template<int BN, int ACT, bool OUT_BF16, bool RESID>
__global__ __launch_bounds__(256) void gemm_bt(
    const unsigned short* __restrict__ A, const unsigned short* __restrict__ BT,
    const float* __restrict__ bias, const float* __restrict__ resid,
    void* __restrict__ Cout, int M, int N, int K)
{
  constexpr int NI = BN / 32;            // 4 (BN=128) or 2 (BN=64)
  __shared__ unsigned short As[128][32];
  __shared__ unsigned short Bs[BN][32];
  const int m0 = blockIdx.x * 128, n0 = blockIdx.y * BN;
  const int tid = threadIdx.x, lane = tid & 63, wave = tid >> 6;
  const int l15 = lane & 15, lg = lane >> 4;
  int wm, wn;
  if (BN == 128) { wm = (wave >> 1) * 64; wn = (wave & 1) * 64; }
  else           { wm = (wave & 1) * 64;  wn = (wave >> 1) * 32; }
  f32x4 acc[4][NI];
#pragma unroll
  for (int i = 0; i < 4; i++)
#pragma unroll
    for (int j = 0; j < NI; j++) acc[i][j] = (f32x4){0.f, 0.f, 0.f, 0.f};

  const int srow = lane >> 2;            // 0..15
  const int scol = (lane & 3) * 8;       // 0,8,16,24
  const unsigned short* Ag = A + (size_t)(m0 + wave * 32 + srow) * K + scol;
  unsigned short* Al = &As[wave * 32 + srow][scol];
  const unsigned short* Bg;
  unsigned short* Bl;
  if (BN == 128) { Bg = BT + (size_t)(n0 + wave * 32 + srow) * K + scol; Bl = &Bs[wave * 32 + srow][0] + scol; }
  else           { Bg = BT + (size_t)(n0 + wave * 16 + srow) * K + scol; Bl = &Bs[wave * 16 + srow][0] + scol; }
  const size_t kstride16 = (size_t)16 * K;

  for (int k0 = 0; k0 < K; k0 += 32) {
    __syncthreads();
    gl_lds16(Ag + k0, Al);
    gl_lds16(Ag + k0 + kstride16, Al + 16 * 32);
    gl_lds16(Bg + k0, Bl);
    if (BN == 128) gl_lds16(Bg + k0 + kstride16, Bl + 16 * 32);
    __syncthreads();
    bf16x8 af[4], bfr[NI];
#pragma unroll
    for (int mi = 0; mi < 4; mi++)
      af[mi] = *(const bf16x8*)&As[wm + mi * 16 + l15][lg * 8];
#pragma unroll
    for (int ni = 0; ni < NI; ni++)
      bfr[ni] = *(const bf16x8*)&Bs[wn + ni * 16 + l15][lg * 8];
#pragma unroll
    for (int mi = 0; mi < 4; mi++)
#pragma unroll
      for (int ni = 0; ni < NI; ni++)
        acc[mi][ni] = __builtin_amdgcn_mfma_f32_16x16x32_bf16(af[mi], bfr[ni], acc[mi][ni], 0, 0, 0);
  }

#pragma unroll
  for (int ni = 0; ni < NI; ni++) {
    const int col = n0 + wn + ni * 16 + l15;
    const float bv = bias ? bias[col] : 0.0f;
#pragma unroll
    for (int mi = 0; mi < 4; mi++) {
      const int rbase = m0 + wm + mi * 16 + lg * 4;
#pragma unroll
      for (int r = 0; r < 4; r++) {
        float v = acc[mi][ni][r] + bv;
        if (ACT == 2) v = 0.5f * v * (1.0f + erff(v * 0.70710678118654752f));
        const size_t idx = (size_t)(rbase + r) * N + col;
        if (RESID) v += resid[idx];
        if (OUT_BF16) ((unsigned short*)Cout)[idx] = f2bf(v);
        else          ((float*)Cout)[idx] = v;
      }
    }
  }
}

// ---------------------------------------------------------------------------
// Windowed causal attention, all-MFMA. One block per (16-query tile, h, b).
// QK^T MFMA -> f32 scores in LDS -> softmax -> bf16 P (aliased over S) ->
// PV MFMA from LDS-staged V window. XCD-chunked blockIdx.x swizzle.
// ---------------------------------------------------------------------------
__global__ __launch_bounds__(256) void attn_kernel(
    const unsigned short* __restrict__ qkvgu, unsigned short* __restrict__ ao)
{
  __shared__ float S[16][276];             // also holds P bf16 (552 elem/row)
  __shared__ unsigned short Vt[288][68];   // V window rows, 8B-aligned stride
  unsigned short* P = (unsigned short*)&S[0][0];

  const int bx = ((blockIdx.x & 7) << 4) | (blockIdx.x >> 3);  // XCD chunking
  const int q0 = bx * 16;
  const int h  = blockIdx.y;
  const int b  = blockIdx.z;
  const int tid = threadIdx.x, lane = tid & 63, wave = tid >> 6;
  const int l15 = lane & 15, lg = lane >> 4;
  const size_t rowbase = (size_t)b * T_LEN;

  // ---- stage V window (272 rows + 16 zero rows) into Vt ----
  {
    const int cg = (tid & 3) * 16;
    const int rr = tid >> 2;
#pragma unroll
    for (int j = 0; j < 5; j++) {
      const int row = j * 64 + rr;
      if (row < 288) {
        const int vrow = q0 - 256 + row;
        uint4 d0 = {0u, 0u, 0u, 0u}, d1 = {0u, 0u, 0u, 0u};
        if (vrow >= 0 && row < 272) {
          const unsigned short* vp = qkvgu + (rowbase + vrow) * N_CAT + 2048 + h * 64 + cg;
          d0 = *(const uint4*)vp;
          d1 = *(const uint4*)(vp + 8);
        }
        unsigned short* wp = &Vt[row][cg];
        ((uint2*)wp)[0] = make_uint2(d0.x, d0.y);
        ((uint2*)wp)[1] = make_uint2(d0.z, d0.w);
        ((uint2*)wp)[2] = make_uint2(d1.x, d1.y);
        ((uint2*)wp)[3] = make_uint2(d1.z, d1.w);
      }
    }
  }

  // ---- QK^T (each wave: ktiles wave, wave+4, ...) ----
  {
    const unsigned short* qp = qkvgu + (rowbase + q0 + l15) * N_CAT + h * 64 + lg * 8;
    const bf16x8 aq0 = *(const bf16x8*)qp;
    const bf16x8 aq1 = *(const bf16x8*)(qp + 32);
    for (int kt = wave; kt < 17; kt += 4) {
      const int kbase = q0 - 256 + kt * 16;
      const int krow = kbase + l15;
      const int krc = krow < 0 ? 0 : krow;
      const unsigned short* kp = qkvgu + (rowbase + krc) * N_CAT + 1024 + h * 64 + lg * 8;
      const bf16x8 bk0 = *(const bf16x8*)kp;
      const bf16x8 bk1 = *(const bf16x8*)(kp + 32);
      f32x4 sacc = (f32x4){0.f, 0.f, 0.f, 0.f};
      sacc = __builtin_amdgcn_mfma_f32_16x16x32_bf16(aq0, bk0, sacc, 0, 0, 0);
      sacc = __builtin_amdgcn_mfma_f32_16x16x32_bf16(aq1, bk1, sacc, 0, 0, 0);
#pragma unroll
      for (int r = 0; r < 4; r++) {
        const int qi = q0 + lg * 4 + r;
        const int kj = kbase + l15;
        const bool ok = (kj >= 0) && (kj <= qi) && (qi - kj < WINDOW);
        S[lg * 4 + r][kt * 16 + l15] = ok ? sacc[r] * 0.125f : -1e30f;
      }
    }
  }
  __syncthreads();

  // ---- softmax per row; write P bf16 aliased over S (writes trail reads) ----
  {
    const int q = tid >> 4, sub = tid & 15;
    float mx = -1e30f;
    for (int c = sub; c < 272; c += 16) mx = fmaxf(mx, S[q][c]);
#pragma unroll
    for (int off = 8; off >= 1; off >>= 1) mx = fmaxf(mx, __shfl_xor(mx, off));
    float sum = 0.f;
    for (int c = sub; c < 272; c += 16) sum += __expf(S[q][c] - mx);
#pragma unroll
    for (int off = 8; off >= 1; off >>= 1) sum += __shfl_xor(sum, off);
    const float inv = 1.0f / sum;
    unsigned short* Prow = P + q * 552;
    for (int c = sub; c < 288; c += 16) {
      const float pv = (c < 272) ? __expf(S[q][c] - mx) * inv : 0.0f;
      Prow[c] = f2bf(pv);
    }
  }
  __syncthreads();

  // ---- PV via MFMA: wave handles d-dims [wave*16, wave*16+16) ----
  {
    f32x4 oacc = (f32x4){0.f, 0.f, 0.f, 0.f};
    const int dn = wave * 16 + l15;
#pragma unroll
    for (int ks = 0; ks < 9; ks++) {
      const bf16x8 pa = *(const bf16x8*)(P + l15 * 552 + ks * 32 + lg * 8);
      bf16x8 vb;
      const int kb = ks * 32 + lg * 8;
#pragma unroll
      for (int j = 0; j < 8; j++) ((unsigned short*)&vb)[j] = Vt[kb + j][dn];
      oacc = __builtin_amdgcn_mfma_f32_16x16x32_bf16(pa, vb, oacc, 0, 0, 0);
    }
#pragma unroll
    for (int r = 0; r < 4; r++)
      ao[(rowbase + q0 + lg * 4 + r) * D_MODEL + h * 64 + dn] = f2bf(oacc[r]);
  }
}

// ---------------------------------------------------------------------------
// Chunked SSM scan: 4 chunks of 512; |A|<0.1 => A^512 == 0 in f32, so the
// carry into chunk c is exactly chunk c-1's local final. Fixup adds
// A^(tau+1)*carry and self-terminates on underflow (~45 iters).
// ---------------------------------------------------------------------------
__global__ __launch_bounds__(1024) void scan_kernel(
    const unsigned short* __restrict__ qkvgu, const float* __restrict__ Avec,
    const float* __restrict__ s0, unsigned short* __restrict__ states,
    float* __restrict__ out_state)
{
  __shared__ float finals[4][256];
  const int tid = threadIdx.x;
  const int bn = tid & 255;
  const int b = bn >> 7, n = bn & 127;
  const int c = tid >> 8;
  const float a = Avec[n];
  float s = (c == 0) ? s0[bn] : 0.0f;
  const size_t ubase = (size_t)b * T_LEN * N_CAT + 4096 + n;
  unsigned short* sp = states + (size_t)b * T_LEN * N_STATE + n;
  const int t0 = c * 512;
#pragma unroll 8
  for (int t = t0; t < t0 + 512; t++) {
    s = fmaf(a, s, bf2f(qkvgu[ubase + (size_t)t * N_CAT]));
    sp[(size_t)t * N_STATE] = f2bf(s);
  }
  finals[c][bn] = s;
  if (c == 3) out_state[bn] = s;
  __syncthreads();
  if (c > 0) {
    const float carry = finals[c - 1][bn];
    float f = a;
    for (int t = t0; t < t0 + 512; t++) {
      if (f == 0.0f) break;
      const float v = bf2f(sp[(size_t)t * N_STATE]) + f * carry;
      sp[(size_t)t * N_STATE] = f2bf(v);
      f *= a;
    }
  }
}

// ---------------------------------------------------------------------------
// Gated fusion: out = x + g*attn + (1-g)*ssm,  g = sigmoid(xg)
// ---------------------------------------------------------------------------
__global__ __launch_bounds__(256) void fusion_kernel(
    const float* __restrict__ x, const unsigned short* __restrict__ qkvgu,
    const unsigned short* __restrict__ attn, const unsigned short* __restrict__ ssm,
    float* __restrict__ out)
{
  const int i = blockIdx.x * 256 + threadIdx.x;
  const size_t e4 = (size_t)i * 4;
  const int row = i >> 8;
  const int col = (i & 255) * 4;
  const float4 xv = *(const float4*)(x + e4);
  const ushort4 au = *(const ushort4*)(attn + e4);
  const ushort4 su = *(const ushort4*)(ssm + e4);
  const ushort4 gu = *(const ushort4*)(qkvgu + (size_t)row * N_CAT + 3072 + col);
  float4 o;
  const float g0 = 1.0f / (1.0f + __expf(-bf2f(gu.x)));
  const float g1 = 1.0f / (1.0f + __expf(-bf2f(gu.y)));
  const float g2 = 1.0f / (1.0f + __expf(-bf2f(gu.z)));
  const float g3 = 1.0f / (1.0f + __expf(-bf2f(gu.w)));
  o.x = xv.x + g0 * bf2f(au.x) + (1.0f - g0) * bf2f(su.x);
  o.y = xv.y + g1 * bf2f(au.y) + (1.0f - g1) * bf2f(su.y);
  o.z = xv.z + g2 * bf2f(au.z) + (1.0f - g2) * bf2f(su.z);
  o.w = xv.w + g3 * bf2f(au.w) + (1.0f - g3) * bf2f(su.w);
  *(float4*)(out + e4) = o;
}

// ---------------------------------------------------------------------------
extern "C" void kernel_launch(void* const* d_in, const int* in_sizes, int n_in,
                              void* d_out, int out_size, void* d_ws, size_t ws_size,
                              hipStream_t stream)
{
  const float* x     = (const float*)d_in[0];
  const float* ssm0  = (const float*)d_in[1];
  const float* ln1_g = (const float*)d_in[2];
  const float* ln1_b = (const float*)d_in[3];
  const float* wq    = (const float*)d_in[4];
  const float* bq    = (const float*)d_in[5];
  const float* wk    = (const float*)d_in[6];
  const float* bk    = (const float*)d_in[7];
  const float* wv    = (const float*)d_in[8];
  const float* bv    = (const float*)d_in[9];
  const float* wo    = (const float*)d_in[10];
  const float* bo    = (const float*)d_in[11];
  const float* wg    = (const float*)d_in[12];
  const float* bg    = (const float*)d_in[13];
  const float* Av    = (const float*)d_in[14];
  const float* Bw    = (const float*)d_in[15];
  const float* Cw    = (const float*)d_in[16];
  const float* ln2_g = (const float*)d_in[17];
  const float* ln2_b = (const float*)d_in[18];
  const float* w1    = (const float*)d_in[19];
  const float* b1    = (const float*)d_in[20];
  const float* w2    = (const float*)d_in[21];
  const float* b2    = (const float*)d_in[22];

  char* p = (char*)d_ws;
  auto take = [&](size_t bytes) { char* q = p; p += (bytes + 255) & ~(size_t)255; return q; };
  unsigned short* WcatT  = (unsigned short*)take((size_t)N_CAT * 1024 * 2);
  unsigned short* woT    = (unsigned short*)take((size_t)1024 * 1024 * 2);
  unsigned short* CwT    = (unsigned short*)take((size_t)1024 * 128 * 2);
  unsigned short* w1T    = (unsigned short*)take((size_t)4096 * 1024 * 2);
  unsigned short* w2T    = (unsigned short*)take((size_t)1024 * 4096 * 2);
  float*          bcat   = (float*)take((size_t)N_CAT * 4);
  unsigned short* xn     = (unsigned short*)take((size_t)M_ROWS * 1024 * 2);
  unsigned short* qkvgu  = (unsigned short*)take((size_t)M_ROWS * N_CAT * 2);
  unsigned short* ao     = (unsigned short*)take((size_t)M_ROWS * 1024 * 2);
  unsigned short* states = (unsigned short*)take((size_t)M_ROWS * N_STATE * 2);
  unsigned short* attn_o = (unsigned short*)take((size_t)M_ROWS * 1024 * 2);
  unsigned short* ssm_o  = (unsigned short*)take((size_t)M_ROWS * 1024 * 2);
  unsigned short* hbuf   = qkvgu;   // alias: qkvgu dead after fusion

  float* outx = (float*)d_out;
  float* out_state = outx + (size_t)M_ROWS * 1024;

  // --- weight prep (bf16, transposed) ---
  transpose_cvt<<<dim3(32, 32), 256, 0, stream>>>(wq, WcatT, 1024, 1024, 0, 1024);
  transpose_cvt<<<dim3(32, 32), 256, 0, stream>>>(wk, WcatT, 1024, 1024, 1024, 1024);
  transpose_cvt<<<dim3(32, 32), 256, 0, stream>>>(wv, WcatT, 1024, 1024, 2048, 1024);
  transpose_cvt<<<dim3(32, 32), 256, 0, stream>>>(wg, WcatT, 1024, 1024, 3072, 1024);
  transpose_cvt<<<dim3(32, 4), 256, 0, stream>>>(Bw, WcatT, 1024, 128, 4096, 1024);
  transpose_cvt<<<dim3(32, 32), 256, 0, stream>>>(wo, woT, 1024, 1024, 0, 1024);
  transpose_cvt<<<dim3(4, 32), 256, 0, stream>>>(Cw, CwT, 128, 1024, 0, 128);
  transpose_cvt<<<dim3(32, 128), 256, 0, stream>>>(w1, w1T, 1024, 4096, 0, 1024);
  transpose_cvt<<<dim3(128, 32), 256, 0, stream>>>(w2, w2T, 4096, 1024, 0, 4096);
  build_bcat<<<17, 256, 0, stream>>>(bq, bk, bv, bg, bcat);

  // --- forward ---
  ln_kernel<<<M_ROWS, 256, 0, stream>>>(x, ln1_g, ln1_b, xn);
  gemm_bt<128, 0, true, false><<<dim3(32, 33), 256, 0, stream>>>(
      xn, WcatT, bcat, nullptr, qkvgu, M_ROWS, N_CAT, 1024);
  attn_kernel<<<dim3(128, 16, 2), 256, 0, stream>>>(qkvgu, ao);
  scan_kernel<<<1, 1024, 0, stream>>>(qkvgu, Av, ssm0, states, out_state);
  gemm_bt<64, 0, true, false><<<dim3(32, 16), 256, 0, stream>>>(
      ao, woT, bo, nullptr, attn_o, M_ROWS, 1024, 1024);
  gemm_bt<64, 0, true, false><<<dim3(32, 16), 256, 0, stream>>>(
      states, CwT, nullptr, nullptr, ssm_o, M_ROWS, 1024, 128);
  fusion_kernel<<<4096, 256, 0, stream>>>(x, qkvgu, attn_o, ssm_o, outx);
  ln_kernel<<<M_ROWS, 256, 0, stream>>>(outx, ln2_g, ln2_b, xn);
  gemm_bt<128, 2, true, false><<<dim3(32, 32), 256, 0, stream>>>(
      xn, w1T, b1, nullptr, hbuf, M_ROWS, D_FF, 1024);
  gemm_bt<64, 0, false, true><<<dim3(32, 16), 256, 0, stream>>>(
      hbuf, w2T, b2, outx, outx, M_ROWS, 1024, D_FF);
}